// Round 6
// baseline (623.236 us; speedup 1.0000x reference)
//
#include <hip/hip_runtime.h>

// StackMemory pipeline for MI355X (gfx950).
// B=4, S=2048, H=1024, NH=16, SLOTS=16, SD=32, HD=64. 8192 tokens.
//
// Two-kernel structure (fusion measured SLOWER: 285us fused vs ~208us split):
//   proj_kernel : action logits (raw, scaled) + k projection for all tokens,
//                 stashed into the new_stack OUTPUT region (slot0 = k,
//                 slot1[0:3] = logits). Each (tok,head) slice is read then
//                 fully overwritten by the SAME wave in stack_main.
//   stack_main  : TWO (token,head) units per wave. Lane l <-> float4
//                 (slot=l>>3, q=l&7). KEY CHANGE vs R5: the slot-shift
//                 neighbor rows are DIRECT GLOBAL LOADS at +/-128 B (slots
//                 are contiguous, so stk4[l+8] crosses the slot7->8 boundary
//                 correctly) -- L1 hits in already-fetched lines. This
//                 deletes the ~30-op/unit DS shuffle network that was
//                 co-bottlenecking with HBM. Mask neighbors likewise loaded
//                 (clamped). Reduce stages use permlane32_swap on VALU.
//
// Outputs concatenated flat: out [8192*1024] | new_stack [8192*8192] | new_mask [8192*256]

constexpr long long OUT_STACK_OFF = 8388608LL;     // 4*2048*1024
constexpr long long OUT_MASK_OFF  = 75497472LL;    // + 4*2048*16*16*32

__global__ void transpose_wa(const float* __restrict__ Wa, float* __restrict__ WaT) {
    int o = blockIdx.x * 256 + threadIdx.x;        // 48*1024 elements
    if (o < 48 * 1024) {
        int j = o >> 10, i = o & 1023;
        WaT[o] = Wa[i * 48 + j];
    }
}

__device__ __forceinline__ float dot4(float4 a, float4 b) {
    return a.x * b.x + a.y * b.y + a.z * b.z + a.w * b.w;
}

__device__ __forceinline__ float4 sel4(bool c, float4 a, float4 b) {
    return make_float4(c ? a.x : b.x, c ? a.y : b.y, c ? a.z : b.z, c ? a.w : b.w);
}

// xor-32 reduce stage on the VALU pipe (v_permlane32_swap) when available.
#if defined(__has_builtin) && __has_builtin(__builtin_amdgcn_permlane32_swap)
typedef int v2i_t __attribute__((ext_vector_type(2)));
__device__ __forceinline__ float red32_add(float x) {
    v2i_t r = __builtin_amdgcn_permlane32_swap(__float_as_int(x), __float_as_int(x),
                                               false, false);
    return __int_as_float(r.x) + __int_as_float(r.y);
}
__device__ __forceinline__ float red32_max(float x) {
    v2i_t r = __builtin_amdgcn_permlane32_swap(__float_as_int(x), __float_as_int(x),
                                               false, false);
    return fmaxf(__int_as_float(r.x), __int_as_float(r.y));
}
#else
__device__ __forceinline__ float red32_add(float x) { return x + __shfl_xor(x, 32); }
__device__ __forceinline__ float red32_max(float x) { return fmaxf(x, __shfl_xor(x, 32)); }
#endif

// ---------------------------------------------------------------------------
// Phase 1: raw scaled logits + k projection, 4 tokens per block (amortizes
// the 192 KB WaT read 4x). No LDS -> high residency.  (passed R1/R5)
// ---------------------------------------------------------------------------
__global__ __launch_bounds__(256)
void proj_kernel(const float* __restrict__ hid,
                 const float* __restrict__ WaT,   // [48][1024]
                 const float* __restrict__ ba,    // [48]
                 const float* __restrict__ Wd,    // [64][32]
                 const float* __restrict__ bd,    // [32]
                 float* __restrict__ out)
{
    const int t = threadIdx.x;
    const int wv = t >> 6, lane = t & 63;
    const int tok0 = blockIdx.x * 4;
    float* stash = out + OUT_STACK_OFF;
    const float4* hid4 = (const float4*)hid + (size_t)tok0 * 256;

    float4 hreg[4][4];
    #pragma unroll
    for (int tt = 0; tt < 4; ++tt)
        #pragma unroll
        for (int m = 0; m < 4; ++m)
            hreg[tt][m] = hid4[tt * 256 + m * 64 + lane];

    // ---- logits: wave wv computes j in [12wv, 12wv+12) for all 4 tokens ----
    const float4* waT4 = (const float4*)WaT;
    #pragma unroll
    for (int jj = 0; jj < 12; ++jj) {
        int j = wv * 12 + jj;
        float a0 = 0.f, a1 = 0.f, a2 = 0.f, a3 = 0.f;
        #pragma unroll
        for (int m = 0; m < 4; ++m) {
            float4 w = waT4[j * 256 + m * 64 + lane];
            a0 += dot4(hreg[0][m], w);
            a1 += dot4(hreg[1][m], w);
            a2 += dot4(hreg[2][m], w);
            a3 += dot4(hreg[3][m], w);
        }
        #pragma unroll
        for (int off = 1; off <= 16; off <<= 1) {
            a0 += __shfl_xor(a0, off);
            a1 += __shfl_xor(a1, off);
            a2 += __shfl_xor(a2, off);
            a3 += __shfl_xor(a3, off);
        }
        a0 = red32_add(a0); a1 = red32_add(a1); a2 = red32_add(a2); a3 = red32_add(a3);
        if ((lane & 15) == jj) {                 // lanes jj, jj+16, jj+32, jj+48
            int tt = lane >> 4;
            float v = (tt == 0) ? a0 : (tt == 1) ? a1 : (tt == 2) ? a2 : a3;
            int nh = wv * 4 + jj / 3, a = jj - 3 * (jj / 3);
            stash[(size_t)(tok0 + tt) * 8192 + nh * 512 + 32 + a] = (v + ba[j]) * 0.125f;
        }
    }

    // ---- k projection: thread -> dim d = t&31, heads nhg and nhg+8, 4 tokens ----
    const int d = t & 31, nhg = t >> 5;
    float acc0[4], acc1[4];
    float bdv = bd[d];
    #pragma unroll
    for (int tt = 0; tt < 4; ++tt) { acc0[tt] = bdv; acc1[tt] = bdv; }
    #pragma unroll
    for (int ii = 0; ii < 16; ++ii) {
        float w0 = Wd[(4 * ii + 0) * 32 + d];
        float w1 = Wd[(4 * ii + 1) * 32 + d];
        float w2 = Wd[(4 * ii + 2) * 32 + d];
        float w3 = Wd[(4 * ii + 3) * 32 + d];
        #pragma unroll
        for (int tt = 0; tt < 4; ++tt) {
            float4 ha = hid4[tt * 256 + nhg * 16 + ii];        // broadcast, L1-hot
            float4 hb = hid4[tt * 256 + (nhg + 8) * 16 + ii];
            acc0[tt] += ha.x * w0 + ha.y * w1 + ha.z * w2 + ha.w * w3;
            acc1[tt] += hb.x * w0 + hb.y * w1 + hb.z * w2 + hb.w * w3;
        }
    }
    #pragma unroll
    for (int tt = 0; tt < 4; ++tt) {
        stash[(size_t)(tok0 + tt) * 8192 + nhg * 512 + d] = acc0[tt];
        stash[(size_t)(tok0 + tt) * 8192 + (nhg + 8) * 512 + d] = acc1[tt];
    }
}

// ---------------------------------------------------------------------------
// Phase 2: TWO (token,head) units per wave. Lane l <-> float4 (slot=l>>3, q=l&7).
// Block = 4 waves = 8 units = half a token's heads.
// ---------------------------------------------------------------------------
__global__ __launch_bounds__(256, 4)
void stack_main(const float* __restrict__ stack,
                const float* __restrict__ mask,
                const float* __restrict__ hid,
                const float* __restrict__ Wg,    // [32]
                const float* __restrict__ bgp,   // [1]
                const float* __restrict__ Wu,    // [32][64]
                const float* __restrict__ bu,    // [64]
                const float* __restrict__ resw,  // [1]
                float* __restrict__ out)
{
    __shared__ __align__(16) float sh_mem[4][2][32];
    const int t = threadIdx.x, wv = t >> 6, l = t & 63;
    const int bid = blockIdx.x;
    const int tok = bid >> 1;
    const int nhb = ((bid & 1) << 3) + wv;        // nh of unit 0; unit 1 = +4

    const float4* stkt = (const float4*)stack + (size_t)tok * 2048;
    float* ostack_base = out + OUT_STACK_OFF + (size_t)tok * 8192;
    const float* mrow_g = mask + (size_t)tok * 256;

    const bool lo = (l < 8), hi = (l >= 56);
    const int slt = l >> 3;                       // slot within A-half (0..7)
    const int iP1 = lo ? 0 : (l - 8);             // prevA row (clamped; lo uses kv)
    const int iN2 = hi ? 127 : (72 + l);          // nextB row (clamped; hi -> zero)

    // ---- issue ALL global loads for both units up front ----
    // Neighbor rows are direct loads: slots 0..15 contiguous, so stk4[l+8]
    // covers slots 1..8 (crossing the A/B boundary) with no special case.
    float4 A[2], Bv[2], P1[2], N1[2], P2[2], N2[2], kv[2], lgv[2];
    float mA[2], mB[2], pmAr[2], nmAr[2], pmBr[2], nmBr[2];
    #pragma unroll
    for (int u = 0; u < 2; ++u) {
        const int nh = nhb + 4 * u;
        const float4* stk4 = stkt + nh * 128;
        A[u]  = stk4[l];                          // slots 0..7   (1 KB coalesced)
        Bv[u] = stk4[64 + l];                     // slots 8..15
        P1[u] = stk4[iP1];                        // slots -1..6  (L1 hit)
        N1[u] = stk4[l + 8];                      // slots 1..8   (L1 hit)
        P2[u] = stk4[56 + l];                     // slots 7..14  (L1 hit)
        N2[u] = stk4[iN2];                        // slots 9..16  (L1 hit, clamped)
        const float4* stash4 = (const float4*)(ostack_base + nh * 512);
        kv[u]  = stash4[l & 7];                   // k quarter (stash, ours to overwrite)
        lgv[u] = stash4[8];                       // raw logits in .x .y .z
        const int mb = nh * 16;
        mA[u]  = mrow_g[mb + slt];
        mB[u]  = mrow_g[mb + 8 + slt];
        pmAr[u] = mrow_g[mb + (lo ? 0 : slt - 1)];
        nmAr[u] = mrow_g[mb + slt + 1];           // slot7 -> mask[8], valid
        pmBr[u] = mrow_g[mb + 7 + slt];
        nmBr[u] = mrow_g[(mb + 9 + slt) > 255 ? 255 : (mb + 9 + slt)];  // clamp last head
    }
    const float4 wg = *(const float4*)(Wg + (l & 7) * 4);
    const float bgv = bgp[0];
    const float4 z4 = make_float4(0.f, 0.f, 0.f, 0.f);

    // ---- action softmax (VALU only, wave-uniform per unit) ----
    float ap[2], apop[2], an[2];
    #pragma unroll
    for (int u = 0; u < 2; ++u) {
        float mx = fmaxf(lgv[u].x, fmaxf(lgv[u].y, lgv[u].z));
        float e0 = __expf(lgv[u].x - mx), e1 = __expf(lgv[u].y - mx), e2 = __expf(lgv[u].z - mx);
        float ainv = 1.f / (e0 + e1 + e2);
        ap[u] = e0 * ainv; apop[u] = e1 * ainv; an[u] = e2 * ainv;
    }

    // ---- stack update + stores (no DS ops in this phase at all) ----
    float4 nA[2], nB[2];
    float nmaskA[2], nmaskB[2];
    #pragma unroll
    for (int u = 0; u < 2; ++u) {
        float4 prevA = sel4(lo, kv[u], P1[u]);
        float4 nextA = N1[u];
        float4 prevB = P2[u];
        float4 nextB = sel4(hi, z4, N2[u]);
        float pmA = lo ? 1.f : pmAr[u];
        float nmA = nmAr[u];
        float pmB = pmBr[u];
        float nmB = hi ? 0.f : nmBr[u];

        nA[u].x = ap[u] * prevA.x + apop[u] * nextA.x + an[u] * A[u].x;
        nA[u].y = ap[u] * prevA.y + apop[u] * nextA.y + an[u] * A[u].y;
        nA[u].z = ap[u] * prevA.z + apop[u] * nextA.z + an[u] * A[u].z;
        nA[u].w = ap[u] * prevA.w + apop[u] * nextA.w + an[u] * A[u].w;
        nB[u].x = ap[u] * prevB.x + apop[u] * nextB.x + an[u] * Bv[u].x;
        nB[u].y = ap[u] * prevB.y + apop[u] * nextB.y + an[u] * Bv[u].y;
        nB[u].z = ap[u] * prevB.z + apop[u] * nextB.z + an[u] * Bv[u].z;
        nB[u].w = ap[u] * prevB.w + apop[u] * nextB.w + an[u] * Bv[u].w;
        nmaskA[u] = ap[u] * pmA + apop[u] * nmA + an[u] * mA[u];
        nmaskB[u] = ap[u] * pmB + apop[u] * nmB + an[u] * mB[u];

        const int nh = nhb + 4 * u;
        float4* ost4 = (float4*)(ostack_base + nh * 512);
        ost4[l] = nA[u];
        ost4[64 + l] = nB[u];
        if ((l & 7) == 0) {
            float* om = out + OUT_MASK_OFF + (size_t)tok * 256 + nh * 16;
            om[slt] = nmaskA[u];
            om[8 + slt] = nmaskB[u];
        }
    }

    // ---- gate softmax + mem reduce (xor-32 stages on VALU via permlane) ----
    #pragma unroll
    for (int u = 0; u < 2; ++u) {
        float gA = dot4(nA[u], wg);
        float gB = dot4(nB[u], wg);
        #pragma unroll
        for (int off = 1; off <= 4; off <<= 1) {
            gA += __shfl_xor(gA, off);
            gB += __shfl_xor(gB, off);
        }
        gA += bgv + (1.f - nmaskA[u]) * -1e9f;
        gB += bgv + (1.f - nmaskB[u]) * -1e9f;

        float gm = fmaxf(gA, gB);
        gm = fmaxf(gm, __shfl_xor(gm, 8));
        gm = fmaxf(gm, __shfl_xor(gm, 16));
        gm = red32_max(gm);
        float eA = __expf(gA - gm), eB = __expf(gB - gm);
        float es = eA + eB;
        es += __shfl_xor(es, 8);
        es += __shfl_xor(es, 16);
        es = red32_add(es);
        float ginv = 1.f / es;
        float gateA = eA * ginv, gateB = eB * ginv;

        float4 sv;
        sv.x = gateA * nA[u].x + gateB * nB[u].x;
        sv.y = gateA * nA[u].y + gateB * nB[u].y;
        sv.z = gateA * nA[u].z + gateB * nB[u].z;
        sv.w = gateA * nA[u].w + gateB * nB[u].w;
        #pragma unroll
        for (int off = 8; off <= 16; off <<= 1) {
            sv.x += __shfl_xor(sv.x, off);
            sv.y += __shfl_xor(sv.y, off);
            sv.z += __shfl_xor(sv.z, off);
            sv.w += __shfl_xor(sv.w, off);
        }
        sv.x = red32_add(sv.x);
        sv.y = red32_add(sv.y);
        sv.z = red32_add(sv.z);
        sv.w = red32_add(sv.w);
        if (l < 8) *(float4*)&sh_mem[wv][u][l * 4] = sv;   // mem quarter l
    }
    __syncthreads();

    // ---- out = mem @ Wu + bu, * res_weight + hidden; lane -> element l ----
    const float rw = resw[0];
    const float buv = bu[l];
    #pragma unroll
    for (int u = 0; u < 2; ++u) {
        float acc = buv;
        const float4* m4 = (const float4*)sh_mem[wv][u];
        #pragma unroll
        for (int q = 0; q < 8; ++q) {
            float4 mq = m4[q];                    // uniform-address LDS broadcast
            acc += mq.x * Wu[(q * 4 + 0) * 64 + l]
                 + mq.y * Wu[(q * 4 + 1) * 64 + l]
                 + mq.z * Wu[(q * 4 + 2) * 64 + l]
                 + mq.w * Wu[(q * 4 + 3) * 64 + l];
        }
        const int nh = nhb + 4 * u;
        size_t oidx = (size_t)tok * 1024 + nh * 64 + l;
        out[oidx] = acc * rw + hid[oidx];
    }
}

extern "C" void kernel_launch(void* const* d_in, const int* in_sizes, int n_in,
                              void* d_out, int out_size, void* d_ws, size_t ws_size,
                              hipStream_t stream) {
    const float* hid  = (const float*)d_in[0];
    const float* stk  = (const float*)d_in[1];
    const float* msk  = (const float*)d_in[2];
    const float* Wa   = (const float*)d_in[3];
    const float* ba   = (const float*)d_in[4];
    const float* Wd   = (const float*)d_in[5];
    const float* bd   = (const float*)d_in[6];
    const float* Wu   = (const float*)d_in[7];
    const float* bu   = (const float*)d_in[8];
    const float* Wg   = (const float*)d_in[9];
    const float* bg   = (const float*)d_in[10];
    const float* rw   = (const float*)d_in[11];
    float* out = (float*)d_out;
    float* waT = (float*)d_ws;   // 48*1024 floats = 192 KiB scratch

    transpose_wa<<<192, 256, 0, stream>>>(Wa, waT);
    proj_kernel<<<2048, 256, 0, stream>>>(hid, waT, ba, Wd, bd, out);
    stack_main<<<16384, 256, 0, stream>>>(stk, msk, hid, Wg, bg, Wu, bu, rw, out);
}